// Round 4
// baseline (1390.045 us; speedup 1.0000x reference)
//
#include <hip/hip_runtime.h>
#include <hip/hip_bf16.h>

typedef __hip_bfloat16 bf16;

#define NNODES 169
#define NNTOT  338
#define CH     256
#define NH     4
#define NL     3
#define SPAD   176
#define LN_EPS 1e-5f
#define NBLK   256

__device__ __forceinline__ float b2f(bf16 v) { return __bfloat162float(v); }
__device__ __forceinline__ float lrelu(float v) { return fmaxf(v, 0.2f * v); }
__device__ __forceinline__ float ldm(const void* p, size_t i, int isbf) {
    return isbf ? b2f(((const bf16*)p)[i]) : ((const float*)p)[i];
}

// grid-wide barrier: monotonic per-slot counters (zeroed by memset before launch).
// 256 blocks are always co-resident (4 waves/block vs 32-wave/CU capacity),
// so spinning is deadlock-free. Device-scope fences handle cross-XCD L2.
__device__ __forceinline__ void gbar(int* bar, int idx) {
    __syncthreads();
    if (threadIdx.x == 0) {
        __threadfence();
        __hip_atomic_fetch_add(&bar[idx], 1, __ATOMIC_ACQ_REL, __HIP_MEMORY_SCOPE_AGENT);
        while (__hip_atomic_load(&bar[idx], __ATOMIC_ACQUIRE, __HIP_MEMORY_SCOPE_AGENT) < NBLK)
            __builtin_amdgcn_s_sleep(8);
        __threadfence();
    }
    __syncthreads();
}

// ---------------------------------------------------------------- GEMM tile
// out[M,N] tile (bm,bn) = act(A[M,K] @ W[K,N] + bias) (+R). 32x64 tile, BK=32.
// smem: As = smem[0..1151] (32x36), Ws = smem[1152..3199] (32x64).
__device__ void gemm_tile(float* smem,
                          const float* __restrict__ A, const void* __restrict__ Wv, size_t oW,
                          const void* __restrict__ bv_, size_t oB, const float* __restrict__ R,
                          float* __restrict__ out, float* __restrict__ xlT,
                          int M, int K, int N, int bm, int bn,
                          int isbf, int act)
{
    float* As = smem;            // [32][36]
    float* Ws = smem + 1152;     // [32][64]
    const int tid  = threadIdx.x;
    const int row0 = bm * 32, col0 = bn * 64;
    const int c0 = (tid & 15) * 4;
    const int r0 = (tid >> 4) * 2;
    const int ar = tid >> 3;
    const int ak = (tid & 7) * 4;
    const int wk = tid >> 3;
    const int wn = (tid & 7) * 8;

    float acc[2][4] = {{0.f,0.f,0.f,0.f},{0.f,0.f,0.f,0.f}};

    for (int k0 = 0; k0 < K; k0 += 32) {
        float4 av = make_float4(0.f, 0.f, 0.f, 0.f);
        const int gr = row0 + ar;
        if (gr < M) av = *(const float4*)(A + (size_t)gr * K + k0 + ak);
        float wv8[8];
        const size_t widx = oW + (size_t)(k0 + wk) * N + col0 + wn;
        if (isbf) {
            const int4 wi = *(const int4*)((const bf16*)Wv + widx);
            union { unsigned u; float f; } t;
            t.u = ((unsigned)wi.x) << 16;         wv8[0] = t.f;
            t.u = ((unsigned)wi.x) & 0xFFFF0000u; wv8[1] = t.f;
            t.u = ((unsigned)wi.y) << 16;         wv8[2] = t.f;
            t.u = ((unsigned)wi.y) & 0xFFFF0000u; wv8[3] = t.f;
            t.u = ((unsigned)wi.z) << 16;         wv8[4] = t.f;
            t.u = ((unsigned)wi.z) & 0xFFFF0000u; wv8[5] = t.f;
            t.u = ((unsigned)wi.w) << 16;         wv8[6] = t.f;
            t.u = ((unsigned)wi.w) & 0xFFFF0000u; wv8[7] = t.f;
        } else {
            const float* Wf = (const float*)Wv;
            const float4 w0 = *(const float4*)(Wf + widx);
            const float4 w1 = *(const float4*)(Wf + widx + 4);
            wv8[0] = w0.x; wv8[1] = w0.y; wv8[2] = w0.z; wv8[3] = w0.w;
            wv8[4] = w1.x; wv8[5] = w1.y; wv8[6] = w1.z; wv8[7] = w1.w;
        }
        __syncthreads();
        As[ar * 36 + ak + 0] = av.x; As[ar * 36 + ak + 1] = av.y;
        As[ar * 36 + ak + 2] = av.z; As[ar * 36 + ak + 3] = av.w;
        #pragma unroll
        for (int j = 0; j < 8; j++) Ws[wk * 64 + wn + j] = wv8[j];
        __syncthreads();
        #pragma unroll
        for (int k = 0; k < 32; k++) {
            const float a0 = As[r0 * 36 + k];
            const float a1 = As[(r0 + 1) * 36 + k];
            const float4 wv = *(const float4*)&Ws[k * 64 + c0];
            acc[0][0] += a0 * wv.x; acc[0][1] += a0 * wv.y;
            acc[0][2] += a0 * wv.z; acc[0][3] += a0 * wv.w;
            acc[1][0] += a1 * wv.x; acc[1][1] += a1 * wv.y;
            acc[1][2] += a1 * wv.z; acc[1][3] += a1 * wv.w;
        }
    }

    float bv[4];
    #pragma unroll
    for (int j = 0; j < 4; j++) bv[j] = ldm(bv_, oB + col0 + c0 + j, isbf);
    #pragma unroll
    for (int i = 0; i < 2; i++) {
        const int gr = row0 + r0 + i;
        if (gr >= M) continue;
        float4 v;
        v.x = acc[i][0] + bv[0]; v.y = acc[i][1] + bv[1];
        v.z = acc[i][2] + bv[2]; v.w = acc[i][3] + bv[3];
        if (act) {
            v.x = fmaxf(v.x, 0.f); v.y = fmaxf(v.y, 0.f);
            v.z = fmaxf(v.z, 0.f); v.w = fmaxf(v.w, 0.f);
        }
        if (R) {
            const float4 rv = *(const float4*)(R + (size_t)gr * N + col0 + c0);
            v.x += rv.x; v.y += rv.y; v.z += rv.z; v.w += rv.w;
        }
        *(float4*)(out + (size_t)gr * N + col0 + c0) = v;
        if (xlT) {   // scatter transposed copy for the logits phase
            const int col = col0 + c0;
            const int hh = col >> 8, cc = col & 255;
            const int gg = (gr >= NNODES) ? 1 : 0;
            const int ss = gr - gg * NNODES;
            float* tb = xlT + ((size_t)(gg * NH + hh) * CH + cc) * SPAD + ss;
            tb[0] = v.x; tb[SPAD] = v.y; tb[2 * SPAD] = v.z; tb[3 * SPAD] = v.w;
        }
    }
}

// ---------------------------------------------------------------- mega kernel
__global__ __launch_bounds__(256) void k_mega(
    const void* __restrict__ x_in,
    const void* __restrict__ Wl, const void* __restrict__ bl,
    const void* __restrict__ Wr, const void* __restrict__ br,
    const void* __restrict__ att, const void* __restrict__ bias,
    const void* __restrict__ lng, const void* __restrict__ lnb,
    const void* __restrict__ W1, const void* __restrict__ b1,
    const void* __restrict__ W2, const void* __restrict__ b2,
    void* __restrict__ out, int* __restrict__ bar, float* __restrict__ wsf)
{
    __shared__ float smem[4608];
    const int bid = blockIdx.x, tid = threadIdx.x;
    const int lane = tid & 63, wv = tid >> 6;
    const int isbf = ((((const unsigned*)lng)[0] & 0xFFFFu) == 0x3F80u) ? 1 : 0;

    float* x_cur  = wsf;                                   // 338*256
    float* xl     = x_cur + NNTOT * CH;                    // 338*1024
    float* xr     = xl + NNTOT * NH * CH;                  // 338*1024
    float* h_ln   = xr + NNTOT * NH * CH;                  // 338*256
    float* m1     = h_ln + NNTOT * CH;                     // 338*512
    float* xlT    = m1 + NNTOT * 2 * CH;                   // 2*4*256*176
    float* alphaT = xlT + (size_t)2 * NH * CH * SPAD;      // 2*4*169*176

    int bi = 0;

    // ---- convert input to fp32
    for (int i = bid * 256 + tid; i < NNTOT * CH; i += NBLK * 256)
        x_cur[i] = ldm(x_in, (size_t)i, isbf);
    gbar(bar, bi++);

    for (int l = 0; l < NL; l++) {
        const size_t oW  = (size_t)l * CH * NH * CH, oB = (size_t)l * NH * CH;
        const size_t oA  = (size_t)l * NH * CH,      oC = (size_t)l * CH;
        const size_t oW1 = (size_t)l * CH * 2 * CH,  oB1 = (size_t)l * 2 * CH;
        const size_t oW2 = (size_t)l * 2 * CH * CH;

        // ---- phase 1: xl = x@Wl+bl (+transposed copy), xr = x@Wr+br
        for (int u = bid; u < 352; u += NBLK) {
            const int z = u / 176, r = u % 176;
            const int bm = r % 11, bn = r / 11;
            if (z == 0)
                gemm_tile(smem, x_cur, Wl, oW, bl, oB, nullptr, xl, xlT,
                          NNTOT, CH, NH * CH, bm, bn, isbf, 0);
            else
                gemm_tile(smem, x_cur, Wr, oW, br, oB, nullptr, xr, nullptr,
                          NNTOT, CH, NH * CH, bm, bn, isbf, 0);
        }
        gbar(bar, bi++);

        // ---- phase 2: logits + fused softmax -> alphaT[g][h][s][d]
        for (int u = bid; u < 344; u += NBLK) {
            const int d4 = u % 43, h = (u / 43) & 3, g = u / 172;
            const int d0 = d4 * 4;
            float* s_att = smem;                // 256
            float* s_xr  = smem + 256;          // 4*256
            float* s_log = smem + 1280;         // 4*176
            __syncthreads();   // protect smem from previous unit
            s_att[tid] = ldm(att, oA + h * CH + tid, isbf);
            #pragma unroll
            for (int idx = tid; idx < 4 * CH; idx += 256) {
                const int i = idx >> 8, cc = idx & 255;
                const int d = d0 + i;
                s_xr[idx] = (d < NNODES)
                    ? xr[((size_t)(g * NNODES + d)) * (NH * CH) + h * CH + cc] : 0.f;
            }
            __syncthreads();
            const int s = tid;
            if (s < NNODES) {
                float a0 = 0.f, a1 = 0.f, a2 = 0.f, a3 = 0.f;
                const float* xp = xlT + ((size_t)(g * NH + h) * CH) * SPAD + s;
                #pragma unroll 4
                for (int c = 0; c < CH; c++) {
                    const float v = xp[(size_t)c * SPAD];
                    const float a = s_att[c];
                    a0 += a * lrelu(v + s_xr[c]);
                    a1 += a * lrelu(v + s_xr[CH + c]);
                    a2 += a * lrelu(v + s_xr[2 * CH + c]);
                    a3 += a * lrelu(v + s_xr[3 * CH + c]);
                }
                s_log[s] = a0; s_log[SPAD + s] = a1;
                s_log[2 * SPAD + s] = a2; s_log[3 * SPAD + s] = a3;
            }
            __syncthreads();
            // wave wv reduces target row wv (d = d0+wv)
            const int d = d0 + wv;
            const float* row = s_log + wv * SPAD;
            const int s0 = lane, s1 = lane + 64, s2 = lane + 128;
            const float l0 = (s0 < NNODES && s0 != d) ? row[s0] : -1e30f;
            const float l1 = (s1 < NNODES && s1 != d) ? row[s1] : -1e30f;
            const float l2 = (s2 < NNODES && s2 != d) ? row[s2] : -1e30f;
            float mx = fmaxf(l0, fmaxf(l1, l2));
            mx = fmaxf(mx, __shfl_xor(mx, 32)); mx = fmaxf(mx, __shfl_xor(mx, 16));
            mx = fmaxf(mx, __shfl_xor(mx, 8));  mx = fmaxf(mx, __shfl_xor(mx, 4));
            mx = fmaxf(mx, __shfl_xor(mx, 2));  mx = fmaxf(mx, __shfl_xor(mx, 1));
            const float e0 = expf(l0 - mx), e1 = expf(l1 - mx), e2 = expf(l2 - mx);
            float z = e0 + e1 + e2;
            z += __shfl_xor(z, 32); z += __shfl_xor(z, 16); z += __shfl_xor(z, 8);
            z += __shfl_xor(z, 4);  z += __shfl_xor(z, 2);  z += __shfl_xor(z, 1);
            const float sc = 0.25f / (z + 1e-16f);     // head-mean folded in
            if (d < NNODES) {
                float* acol = alphaT + (size_t)(g * NH + h) * NNODES * SPAD + d;
                if (s0 < NNODES) acol[(size_t)s0 * SPAD] = e0 * sc;
                if (s1 < NNODES) acol[(size_t)s1 * SPAD] = e1 * sc;
                if (s2 < NNODES) acol[(size_t)s2 * SPAD] = e2 * sc;
            }
        }
        gbar(bar, bi++);

        // ---- phase 3: aggregate (all 4 heads in-block) + head-sum + bias + LN
        for (int u = bid; u < 86; u += NBLK) {
            const int d4 = u % 43, g = u / 43;
            const int d0 = d4 * 4;
            const int c4 = lane * 4;
            float* s_part = smem;   // [4h][4d][256c] = 4096 floats
            __syncthreads();
            const float* ab = alphaT + (size_t)(g * NH + wv) * NNODES * SPAD + d0;
            const float* xb = xl + (size_t)(g * NNODES) * (NH * CH) + wv * CH + c4;
            float4 A0 = {0,0,0,0}, A1 = {0,0,0,0}, A2 = {0,0,0,0}, A3 = {0,0,0,0};
            for (int s = 0; s < NNODES; s++) {
                const float4 av = *(const float4*)(ab + (size_t)s * SPAD);
                const float4 xv = *(const float4*)(xb + (size_t)s * (NH * CH));
                A0.x += av.x * xv.x; A0.y += av.x * xv.y; A0.z += av.x * xv.z; A0.w += av.x * xv.w;
                A1.x += av.y * xv.x; A1.y += av.y * xv.y; A1.z += av.y * xv.z; A1.w += av.y * xv.w;
                A2.x += av.z * xv.x; A2.y += av.z * xv.y; A2.z += av.z * xv.z; A2.w += av.z * xv.w;
                A3.x += av.w * xv.x; A3.y += av.w * xv.y; A3.z += av.w * xv.z; A3.w += av.w * xv.w;
            }
            *(float4*)&s_part[(wv * 4 + 0) * CH + c4] = A0;
            *(float4*)&s_part[(wv * 4 + 1) * CH + c4] = A1;
            *(float4*)&s_part[(wv * 4 + 2) * CH + c4] = A2;
            *(float4*)&s_part[(wv * 4 + 3) * CH + c4] = A3;
            __syncthreads();
            // wave wv finishes target d0+wv: sum heads + bias, LayerNorm
            const int d = d0 + wv;
            if (d < NNODES) {
                float vch[4];
                float s1 = 0.f, s2 = 0.f;
                #pragma unroll
                for (int j = 0; j < 4; j++) {
                    float v = s_part[(0 * 4 + wv) * CH + c4 + j]
                            + s_part[(1 * 4 + wv) * CH + c4 + j]
                            + s_part[(2 * 4 + wv) * CH + c4 + j]
                            + s_part[(3 * 4 + wv) * CH + c4 + j]
                            + ldm(bias, oC + c4 + j, isbf);
                    vch[j] = v; s1 += v; s2 += v * v;
                }
                s1 += __shfl_xor(s1, 32); s2 += __shfl_xor(s2, 32);
                s1 += __shfl_xor(s1, 16); s2 += __shfl_xor(s2, 16);
                s1 += __shfl_xor(s1, 8);  s2 += __shfl_xor(s2, 8);
                s1 += __shfl_xor(s1, 4);  s2 += __shfl_xor(s2, 4);
                s1 += __shfl_xor(s1, 2);  s2 += __shfl_xor(s2, 2);
                s1 += __shfl_xor(s1, 1);  s2 += __shfl_xor(s2, 1);
                const float mu  = s1 * (1.f / CH);
                const float var = s2 * (1.f / CH) - mu * mu;
                const float rs  = rsqrtf(var + LN_EPS);
                float4 o;
                o.x = (vch[0] - mu) * rs * ldm(lng, oC + c4 + 0, isbf) + ldm(lnb, oC + c4 + 0, isbf);
                o.y = (vch[1] - mu) * rs * ldm(lng, oC + c4 + 1, isbf) + ldm(lnb, oC + c4 + 1, isbf);
                o.z = (vch[2] - mu) * rs * ldm(lng, oC + c4 + 2, isbf) + ldm(lnb, oC + c4 + 2, isbf);
                o.w = (vch[3] - mu) * rs * ldm(lng, oC + c4 + 3, isbf) + ldm(lnb, oC + c4 + 3, isbf);
                *(float4*)(h_ln + (size_t)(g * NNODES + d) * CH + c4) = o;
            }
        }
        gbar(bar, bi++);

        // ---- phase 4: m1 = relu(h_ln@W1+b1)
        for (int u = bid; u < 88; u += NBLK) {
            const int bm = u % 11, bn = u / 11;
            gemm_tile(smem, h_ln, W1, oW1, b1, oB1, nullptr, m1, nullptr,
                      NNTOT, CH, 2 * CH, bm, bn, isbf, 1);
        }
        gbar(bar, bi++);

        // ---- phase 5: x = x + m1@W2+b2
        for (int u = bid; u < 44; u += NBLK) {
            const int bm = u % 11, bn = u / 11;
            gemm_tile(smem, m1, W2, oW2, b2, oC, x_cur, x_cur, nullptr,
                      NNTOT, 2 * CH, CH, bm, bn, isbf, 0);
        }
        gbar(bar, bi++);
    }

    // ---- global mean pool
    if (bid < 2) {
        const int g = bid, c = tid;
        float s = 0.f;
        const float* p = x_cur + (size_t)g * NNODES * CH + c;
        for (int n = 0; n < NNODES; n++) s += p[(size_t)n * CH];
        const float v = s * (1.f / NNODES);
        if (isbf) ((bf16*)out)[g * CH + c] = __float2bfloat16(v);
        else      ((float*)out)[g * CH + c] = v;
    }
}

// ---------------------------------------------------------------- launch
extern "C" void kernel_launch(void* const* d_in, const int* in_sizes, int n_in,
                              void* d_out, int out_size, void* d_ws, size_t ws_size,
                              hipStream_t stream)
{
    int*   bar = (int*)d_ws;                 // 32 barrier slots (128 B)
    float* wsf = (float*)((char*)d_ws + 128);

    hipMemsetAsync(bar, 0, 128, stream);     // barrier counters must start at 0
    k_mega<<<dim3(NBLK), 256, 0, stream>>>(
        d_in[0], d_in[1], d_in[2], d_in[3], d_in[4], d_in[5], d_in[6],
        d_in[7], d_in[8], d_in[9], d_in[10], d_in[11], d_in[12],
        d_out, bar, wsf);
}

// Round 5
// 1003.599 us; speedup vs baseline: 1.3851x; 1.3851x over previous
//
#include <hip/hip_runtime.h>
#include <hip/hip_bf16.h>

typedef __hip_bfloat16 bf16;

#define NNODES 169
#define NNTOT  338
#define CH     256
#define NH     4
#define NL     3
#define SPAD   176
#define LN_EPS 1e-5f
#define NBLK   256

__device__ __forceinline__ float b2f(bf16 v) { return __bfloat162float(v); }
__device__ __forceinline__ float lrelu(float v) { return fmaxf(v, 0.2f * v); }
__device__ __forceinline__ float ldm(const void* p, size_t i, int isbf) {
    return isbf ? b2f(((const bf16*)p)[i]) : ((const float*)p)[i];
}

// grid-wide barrier, monotonic per-slot counters (zeroed by memset pre-launch).
// R4 lesson: spinning with ACQUIRE loads invalidates L1/L2 every probe ->
// 95 MB HBM refetch/dispatch, ~84 us/barrier. Fix: RELEASE publish, RELAXED
// spin (agent-scope atomic load is coherent but emits no cache maintenance),
// then ONE acquire fence per thread after exit.
__device__ __forceinline__ void gbar(int* bar, int idx) {
    __syncthreads();   // all block writes drained (vmcnt(0) before s_barrier)
    if (threadIdx.x == 0) {
        __threadfence();   // release: publish this block's writes device-wide
        __hip_atomic_fetch_add(&bar[idx], 1, __ATOMIC_RELEASE, __HIP_MEMORY_SCOPE_AGENT);
        while (__hip_atomic_load(&bar[idx], __ATOMIC_RELAXED, __HIP_MEMORY_SCOPE_AGENT) < NBLK)
            __builtin_amdgcn_s_sleep(1);
    }
    __syncthreads();
    __threadfence();       // acquire: invalidate stale cached lines once
}

// ---------------------------------------------------------------- GEMM tile
// out[M,N] tile (bm,bn) = act(A[M,K] @ W[K,N] + bias) (+R). 32x64 tile, BK=32.
// smem: As = smem[0..1151] (32x36), Ws = smem[1152..3199] (32x64).
__device__ void gemm_tile(float* smem,
                          const float* __restrict__ A, const void* __restrict__ Wv, size_t oW,
                          const void* __restrict__ bv_, size_t oB, const float* __restrict__ R,
                          float* __restrict__ out, float* __restrict__ xlT,
                          int M, int K, int N, int bm, int bn,
                          int isbf, int act)
{
    float* As = smem;            // [32][36]
    float* Ws = smem + 1152;     // [32][64]
    const int tid  = threadIdx.x;
    const int row0 = bm * 32, col0 = bn * 64;
    const int c0 = (tid & 15) * 4;
    const int r0 = (tid >> 4) * 2;
    const int ar = tid >> 3;
    const int ak = (tid & 7) * 4;
    const int wk = tid >> 3;
    const int wn = (tid & 7) * 8;

    float acc[2][4] = {{0.f,0.f,0.f,0.f},{0.f,0.f,0.f,0.f}};

    for (int k0 = 0; k0 < K; k0 += 32) {
        float4 av = make_float4(0.f, 0.f, 0.f, 0.f);
        const int gr = row0 + ar;
        if (gr < M) av = *(const float4*)(A + (size_t)gr * K + k0 + ak);
        float wv8[8];
        const size_t widx = oW + (size_t)(k0 + wk) * N + col0 + wn;
        if (isbf) {
            const int4 wi = *(const int4*)((const bf16*)Wv + widx);
            union { unsigned u; float f; } t;
            t.u = ((unsigned)wi.x) << 16;         wv8[0] = t.f;
            t.u = ((unsigned)wi.x) & 0xFFFF0000u; wv8[1] = t.f;
            t.u = ((unsigned)wi.y) << 16;         wv8[2] = t.f;
            t.u = ((unsigned)wi.y) & 0xFFFF0000u; wv8[3] = t.f;
            t.u = ((unsigned)wi.z) << 16;         wv8[4] = t.f;
            t.u = ((unsigned)wi.z) & 0xFFFF0000u; wv8[5] = t.f;
            t.u = ((unsigned)wi.w) << 16;         wv8[6] = t.f;
            t.u = ((unsigned)wi.w) & 0xFFFF0000u; wv8[7] = t.f;
        } else {
            const float* Wf = (const float*)Wv;
            const float4 w0 = *(const float4*)(Wf + widx);
            const float4 w1 = *(const float4*)(Wf + widx + 4);
            wv8[0] = w0.x; wv8[1] = w0.y; wv8[2] = w0.z; wv8[3] = w0.w;
            wv8[4] = w1.x; wv8[5] = w1.y; wv8[6] = w1.z; wv8[7] = w1.w;
        }
        __syncthreads();
        As[ar * 36 + ak + 0] = av.x; As[ar * 36 + ak + 1] = av.y;
        As[ar * 36 + ak + 2] = av.z; As[ar * 36 + ak + 3] = av.w;
        #pragma unroll
        for (int j = 0; j < 8; j++) Ws[wk * 64 + wn + j] = wv8[j];
        __syncthreads();
        #pragma unroll
        for (int k = 0; k < 32; k++) {
            const float a0 = As[r0 * 36 + k];
            const float a1 = As[(r0 + 1) * 36 + k];
            const float4 wv = *(const float4*)&Ws[k * 64 + c0];
            acc[0][0] += a0 * wv.x; acc[0][1] += a0 * wv.y;
            acc[0][2] += a0 * wv.z; acc[0][3] += a0 * wv.w;
            acc[1][0] += a1 * wv.x; acc[1][1] += a1 * wv.y;
            acc[1][2] += a1 * wv.z; acc[1][3] += a1 * wv.w;
        }
    }

    float bv[4];
    #pragma unroll
    for (int j = 0; j < 4; j++) bv[j] = ldm(bv_, oB + col0 + c0 + j, isbf);
    #pragma unroll
    for (int i = 0; i < 2; i++) {
        const int gr = row0 + r0 + i;
        if (gr >= M) continue;
        float4 v;
        v.x = acc[i][0] + bv[0]; v.y = acc[i][1] + bv[1];
        v.z = acc[i][2] + bv[2]; v.w = acc[i][3] + bv[3];
        if (act) {
            v.x = fmaxf(v.x, 0.f); v.y = fmaxf(v.y, 0.f);
            v.z = fmaxf(v.z, 0.f); v.w = fmaxf(v.w, 0.f);
        }
        if (R) {
            const float4 rv = *(const float4*)(R + (size_t)gr * N + col0 + c0);
            v.x += rv.x; v.y += rv.y; v.z += rv.z; v.w += rv.w;
        }
        *(float4*)(out + (size_t)gr * N + col0 + c0) = v;
        if (xlT) {   // scatter transposed copy for the logits phase
            const int col = col0 + c0;
            const int hh = col >> 8, cc = col & 255;
            const int gg = (gr >= NNODES) ? 1 : 0;
            const int ss = gr - gg * NNODES;
            float* tb = xlT + ((size_t)(gg * NH + hh) * CH + cc) * SPAD + ss;
            tb[0] = v.x; tb[SPAD] = v.y; tb[2 * SPAD] = v.z; tb[3 * SPAD] = v.w;
        }
    }
}

// ---------------------------------------------------------------- mega kernel
__global__ __launch_bounds__(256) void k_mega(
    const void* __restrict__ x_in,
    const void* __restrict__ Wl, const void* __restrict__ bl,
    const void* __restrict__ Wr, const void* __restrict__ br,
    const void* __restrict__ att, const void* __restrict__ bias,
    const void* __restrict__ lng, const void* __restrict__ lnb,
    const void* __restrict__ W1, const void* __restrict__ b1,
    const void* __restrict__ W2, const void* __restrict__ b2,
    void* __restrict__ out, int* __restrict__ bar, float* __restrict__ wsf)
{
    __shared__ float smem[4608];
    const int bid = blockIdx.x, tid = threadIdx.x;
    const int lane = tid & 63, wv = tid >> 6;
    const int isbf = ((((const unsigned*)lng)[0] & 0xFFFFu) == 0x3F80u) ? 1 : 0;

    float* x_cur  = wsf;                                   // 338*256
    float* xl     = x_cur + NNTOT * CH;                    // 338*1024
    float* xr     = xl + NNTOT * NH * CH;                  // 338*1024
    float* h_ln   = xr + NNTOT * NH * CH;                  // 338*256
    float* m1     = h_ln + NNTOT * CH;                     // 338*512
    float* xlT    = m1 + NNTOT * 2 * CH;                   // 2*4*256*176
    float* alphaT = xlT + (size_t)2 * NH * CH * SPAD;      // 2*4*169*176

    int bi = 0;

    // ---- convert input to fp32
    for (int i = bid * 256 + tid; i < NNTOT * CH; i += NBLK * 256)
        x_cur[i] = ldm(x_in, (size_t)i, isbf);
    gbar(bar, bi++);

    for (int l = 0; l < NL; l++) {
        const size_t oW  = (size_t)l * CH * NH * CH, oB = (size_t)l * NH * CH;
        const size_t oA  = (size_t)l * NH * CH,      oC = (size_t)l * CH;
        const size_t oW1 = (size_t)l * CH * 2 * CH,  oB1 = (size_t)l * 2 * CH;
        const size_t oW2 = (size_t)l * 2 * CH * CH;

        // ---- phase 1: xl = x@Wl+bl (+transposed copy), xr = x@Wr+br
        for (int u = bid; u < 352; u += NBLK) {
            const int z = u / 176, r = u % 176;
            const int bm = r % 11, bn = r / 11;
            if (z == 0)
                gemm_tile(smem, x_cur, Wl, oW, bl, oB, nullptr, xl, xlT,
                          NNTOT, CH, NH * CH, bm, bn, isbf, 0);
            else
                gemm_tile(smem, x_cur, Wr, oW, br, oB, nullptr, xr, nullptr,
                          NNTOT, CH, NH * CH, bm, bn, isbf, 0);
        }
        gbar(bar, bi++);

        // ---- phase 2: logits + fused softmax -> alphaT[g][h][s][d]
        for (int u = bid; u < 344; u += NBLK) {
            const int d4 = u % 43, h = (u / 43) & 3, g = u / 172;
            const int d0 = d4 * 4;
            float* s_att = smem;                // 256
            float* s_xr  = smem + 256;          // 4*256
            float* s_log = smem + 1280;         // 4*176
            __syncthreads();   // protect smem from previous unit
            s_att[tid] = ldm(att, oA + h * CH + tid, isbf);
            #pragma unroll
            for (int idx = tid; idx < 4 * CH; idx += 256) {
                const int i = idx >> 8, cc = idx & 255;
                const int d = d0 + i;
                s_xr[idx] = (d < NNODES)
                    ? xr[((size_t)(g * NNODES + d)) * (NH * CH) + h * CH + cc] : 0.f;
            }
            __syncthreads();
            const int s = tid;
            if (s < NNODES) {
                float a0 = 0.f, a1 = 0.f, a2 = 0.f, a3 = 0.f;
                const float* xp = xlT + ((size_t)(g * NH + h) * CH) * SPAD + s;
                #pragma unroll 4
                for (int c = 0; c < CH; c++) {
                    const float v = xp[(size_t)c * SPAD];
                    const float a = s_att[c];
                    a0 += a * lrelu(v + s_xr[c]);
                    a1 += a * lrelu(v + s_xr[CH + c]);
                    a2 += a * lrelu(v + s_xr[2 * CH + c]);
                    a3 += a * lrelu(v + s_xr[3 * CH + c]);
                }
                s_log[s] = a0; s_log[SPAD + s] = a1;
                s_log[2 * SPAD + s] = a2; s_log[3 * SPAD + s] = a3;
            }
            __syncthreads();
            // wave wv reduces target row wv (d = d0+wv)
            const int d = d0 + wv;
            const float* row = s_log + wv * SPAD;
            const int s0 = lane, s1 = lane + 64, s2 = lane + 128;
            const float l0 = (s0 < NNODES && s0 != d) ? row[s0] : -1e30f;
            const float l1 = (s1 < NNODES && s1 != d) ? row[s1] : -1e30f;
            const float l2 = (s2 < NNODES && s2 != d) ? row[s2] : -1e30f;
            float mx = fmaxf(l0, fmaxf(l1, l2));
            mx = fmaxf(mx, __shfl_xor(mx, 32)); mx = fmaxf(mx, __shfl_xor(mx, 16));
            mx = fmaxf(mx, __shfl_xor(mx, 8));  mx = fmaxf(mx, __shfl_xor(mx, 4));
            mx = fmaxf(mx, __shfl_xor(mx, 2));  mx = fmaxf(mx, __shfl_xor(mx, 1));
            const float e0 = expf(l0 - mx), e1 = expf(l1 - mx), e2 = expf(l2 - mx);
            float z = e0 + e1 + e2;
            z += __shfl_xor(z, 32); z += __shfl_xor(z, 16); z += __shfl_xor(z, 8);
            z += __shfl_xor(z, 4);  z += __shfl_xor(z, 2);  z += __shfl_xor(z, 1);
            const float sc = 0.25f / (z + 1e-16f);     // head-mean folded in
            if (d < NNODES) {
                float* acol = alphaT + (size_t)(g * NH + h) * NNODES * SPAD + d;
                if (s0 < NNODES) acol[(size_t)s0 * SPAD] = e0 * sc;
                if (s1 < NNODES) acol[(size_t)s1 * SPAD] = e1 * sc;
                if (s2 < NNODES) acol[(size_t)s2 * SPAD] = e2 * sc;
            }
        }
        gbar(bar, bi++);

        // ---- phase 3: aggregate (all 4 heads in-block) + head-sum + bias + LN
        for (int u = bid; u < 86; u += NBLK) {
            const int d4 = u % 43, g = u / 43;
            const int d0 = d4 * 4;
            const int c4 = lane * 4;
            float* s_part = smem;   // [4h][4d][256c] = 4096 floats
            __syncthreads();
            const float* ab = alphaT + (size_t)(g * NH + wv) * NNODES * SPAD + d0;
            const float* xb = xl + (size_t)(g * NNODES) * (NH * CH) + wv * CH + c4;
            float4 A0 = {0,0,0,0}, A1 = {0,0,0,0}, A2 = {0,0,0,0}, A3 = {0,0,0,0};
            for (int s = 0; s < NNODES; s++) {
                const float4 av = *(const float4*)(ab + (size_t)s * SPAD);
                const float4 xv = *(const float4*)(xb + (size_t)s * (NH * CH));
                A0.x += av.x * xv.x; A0.y += av.x * xv.y; A0.z += av.x * xv.z; A0.w += av.x * xv.w;
                A1.x += av.y * xv.x; A1.y += av.y * xv.y; A1.z += av.y * xv.z; A1.w += av.y * xv.w;
                A2.x += av.z * xv.x; A2.y += av.z * xv.y; A2.z += av.z * xv.z; A2.w += av.z * xv.w;
                A3.x += av.w * xv.x; A3.y += av.w * xv.y; A3.z += av.w * xv.z; A3.w += av.w * xv.w;
            }
            *(float4*)&s_part[(wv * 4 + 0) * CH + c4] = A0;
            *(float4*)&s_part[(wv * 4 + 1) * CH + c4] = A1;
            *(float4*)&s_part[(wv * 4 + 2) * CH + c4] = A2;
            *(float4*)&s_part[(wv * 4 + 3) * CH + c4] = A3;
            __syncthreads();
            // wave wv finishes target d0+wv: sum heads + bias, LayerNorm
            const int d = d0 + wv;
            if (d < NNODES) {
                float vch[4];
                float s1 = 0.f, s2 = 0.f;
                #pragma unroll
                for (int j = 0; j < 4; j++) {
                    float v = s_part[(0 * 4 + wv) * CH + c4 + j]
                            + s_part[(1 * 4 + wv) * CH + c4 + j]
                            + s_part[(2 * 4 + wv) * CH + c4 + j]
                            + s_part[(3 * 4 + wv) * CH + c4 + j]
                            + ldm(bias, oC + c4 + j, isbf);
                    vch[j] = v; s1 += v; s2 += v * v;
                }
                s1 += __shfl_xor(s1, 32); s2 += __shfl_xor(s2, 32);
                s1 += __shfl_xor(s1, 16); s2 += __shfl_xor(s2, 16);
                s1 += __shfl_xor(s1, 8);  s2 += __shfl_xor(s2, 8);
                s1 += __shfl_xor(s1, 4);  s2 += __shfl_xor(s2, 4);
                s1 += __shfl_xor(s1, 2);  s2 += __shfl_xor(s2, 2);
                s1 += __shfl_xor(s1, 1);  s2 += __shfl_xor(s2, 1);
                const float mu  = s1 * (1.f / CH);
                const float var = s2 * (1.f / CH) - mu * mu;
                const float rs  = rsqrtf(var + LN_EPS);
                float4 o;
                o.x = (vch[0] - mu) * rs * ldm(lng, oC + c4 + 0, isbf) + ldm(lnb, oC + c4 + 0, isbf);
                o.y = (vch[1] - mu) * rs * ldm(lng, oC + c4 + 1, isbf) + ldm(lnb, oC + c4 + 1, isbf);
                o.z = (vch[2] - mu) * rs * ldm(lng, oC + c4 + 2, isbf) + ldm(lnb, oC + c4 + 2, isbf);
                o.w = (vch[3] - mu) * rs * ldm(lng, oC + c4 + 3, isbf) + ldm(lnb, oC + c4 + 3, isbf);
                *(float4*)(h_ln + (size_t)(g * NNODES + d) * CH + c4) = o;
            }
        }
        gbar(bar, bi++);

        // ---- phase 4: m1 = relu(h_ln@W1+b1)
        for (int u = bid; u < 88; u += NBLK) {
            const int bm = u % 11, bn = u / 11;
            gemm_tile(smem, h_ln, W1, oW1, b1, oB1, nullptr, m1, nullptr,
                      NNTOT, CH, 2 * CH, bm, bn, isbf, 1);
        }
        gbar(bar, bi++);

        // ---- phase 5: x = x + m1@W2+b2
        for (int u = bid; u < 44; u += NBLK) {
            const int bm = u % 11, bn = u / 11;
            gemm_tile(smem, m1, W2, oW2, b2, oC, x_cur, x_cur, nullptr,
                      NNTOT, 2 * CH, CH, bm, bn, isbf, 0);
        }
        gbar(bar, bi++);
    }

    // ---- global mean pool
    if (bid < 2) {
        const int g = bid, c = tid;
        float s = 0.f;
        const float* p = x_cur + (size_t)g * NNODES * CH + c;
        for (int n = 0; n < NNODES; n++) s += p[(size_t)n * CH];
        const float v = s * (1.f / NNODES);
        if (isbf) ((bf16*)out)[g * CH + c] = __float2bfloat16(v);
        else      ((float*)out)[g * CH + c] = v;
    }
}

// ---------------------------------------------------------------- launch
extern "C" void kernel_launch(void* const* d_in, const int* in_sizes, int n_in,
                              void* d_out, int out_size, void* d_ws, size_t ws_size,
                              hipStream_t stream)
{
    int*   bar = (int*)d_ws;                 // 32 barrier slots (128 B)
    float* wsf = (float*)((char*)d_ws + 128);

    hipMemsetAsync(bar, 0, 128, stream);     // barrier counters must start at 0
    k_mega<<<dim3(NBLK), 256, 0, stream>>>(
        d_in[0], d_in[1], d_in[2], d_in[3], d_in[4], d_in[5], d_in[6],
        d_in[7], d_in[8], d_in[9], d_in[10], d_in[11], d_in[12],
        d_out, bar, wsf);
}

// Round 6
// 637.680 us; speedup vs baseline: 2.1798x; 1.5738x over previous
//
#include <hip/hip_runtime.h>
#include <hip/hip_bf16.h>

typedef __hip_bfloat16 bf16;

#define NNODES 169
#define NNTOT  338
#define CH     256
#define NH     4
#define NL     3
#define SPAD   176
#define LN_EPS 1e-5f

__device__ __forceinline__ float b2f(bf16 v) { return __bfloat162float(v); }
__device__ __forceinline__ float lrelu(float v) { return fmaxf(v, 0.2f * v); }
__device__ __forceinline__ float ldm(const void* p, size_t i, int isbf) {
    return isbf ? b2f(((const bf16*)p)[i]) : ((const float*)p)[i];
}
// aligned pair load from runtime-dtyped tensor (index must be even)
__device__ __forceinline__ float2 ld2(const void* p, size_t i, int isbf) {
    if (isbf) {
        const unsigned u = *(const unsigned*)((const bf16*)p + i);
        union { unsigned x; float f; } a, b;
        a.x = u << 16; b.x = u & 0xFFFF0000u;
        return make_float2(a.f, b.f);
    }
    return *(const float2*)((const float*)p + i);
}
__device__ __forceinline__ int sniff_bf(const void* lng) {
    return ((((const unsigned*)lng)[0] & 0xFFFFu) == 0x3F80u) ? 1 : 0;
}

// ---------------------------------------------------------------- A: xl/xr GEMM
// xl = x@Wl+bl (+ transposed scatter xlT), xr = x@Wr+br. Tile 32x64, BK=32.
// grid (11,16,2); z picks Wl/Wr. israw: x is the raw (runtime-dtype) input.
__global__ __launch_bounds__(256) void k_gemm_lr(
    const void* __restrict__ Av, int israw,
    const void* __restrict__ Wl, const void* __restrict__ bl,
    const void* __restrict__ Wr, const void* __restrict__ br,
    size_t oW, size_t oB,
    float* __restrict__ xl, float* __restrict__ xr, float* __restrict__ xlT,
    const void* __restrict__ lng)
{
    __shared__ float As[32 * 36];
    __shared__ float Ws[32 * 64];
    const int isbf  = sniff_bf(lng);
    const int a_bf  = israw ? isbf : 0;       // ws activations are fp32
    const int wr    = (blockIdx.z != 0);
    const void* Wv  = wr ? Wr : Wl;
    const void* bv_ = wr ? br : bl;
    float* out      = wr ? xr : xl;

    const int tid  = threadIdx.x;
    const int row0 = blockIdx.x * 32, col0 = blockIdx.y * 64;
    const int c0 = (tid & 15) * 4;
    const int r0 = (tid >> 4) * 2;
    const int ar = tid >> 3;
    const int ak = (tid & 7) * 4;
    const int wk = tid >> 3;
    const int wn = (tid & 7) * 8;
    const int K = CH, N = NH * CH, M = NNTOT;

    float acc[2][4] = {{0.f,0.f,0.f,0.f},{0.f,0.f,0.f,0.f}};

    for (int k0 = 0; k0 < K; k0 += 32) {
        float4 av = make_float4(0.f, 0.f, 0.f, 0.f);
        const int gr = row0 + ar;
        if (gr < M) {
            const size_t ai = (size_t)gr * K + k0 + ak;
            if (israw) {
                av.x = ldm(Av, ai + 0, a_bf); av.y = ldm(Av, ai + 1, a_bf);
                av.z = ldm(Av, ai + 2, a_bf); av.w = ldm(Av, ai + 3, a_bf);
            } else {
                av = *(const float4*)((const float*)Av + ai);
            }
        }
        float wv8[8];
        const size_t widx = oW + (size_t)(k0 + wk) * N + col0 + wn;
        if (isbf) {
            const int4 wi = *(const int4*)((const bf16*)Wv + widx);
            union { unsigned u; float f; } t;
            t.u = ((unsigned)wi.x) << 16;         wv8[0] = t.f;
            t.u = ((unsigned)wi.x) & 0xFFFF0000u; wv8[1] = t.f;
            t.u = ((unsigned)wi.y) << 16;         wv8[2] = t.f;
            t.u = ((unsigned)wi.y) & 0xFFFF0000u; wv8[3] = t.f;
            t.u = ((unsigned)wi.z) << 16;         wv8[4] = t.f;
            t.u = ((unsigned)wi.z) & 0xFFFF0000u; wv8[5] = t.f;
            t.u = ((unsigned)wi.w) << 16;         wv8[6] = t.f;
            t.u = ((unsigned)wi.w) & 0xFFFF0000u; wv8[7] = t.f;
        } else {
            const float* Wf = (const float*)Wv;
            const float4 w0 = *(const float4*)(Wf + widx);
            const float4 w1 = *(const float4*)(Wf + widx + 4);
            wv8[0] = w0.x; wv8[1] = w0.y; wv8[2] = w0.z; wv8[3] = w0.w;
            wv8[4] = w1.x; wv8[5] = w1.y; wv8[6] = w1.z; wv8[7] = w1.w;
        }
        __syncthreads();
        As[ar * 36 + ak + 0] = av.x; As[ar * 36 + ak + 1] = av.y;
        As[ar * 36 + ak + 2] = av.z; As[ar * 36 + ak + 3] = av.w;
        #pragma unroll
        for (int j = 0; j < 8; j++) Ws[wk * 64 + wn + j] = wv8[j];
        __syncthreads();
        #pragma unroll
        for (int k = 0; k < 32; k++) {
            const float a0 = As[r0 * 36 + k];
            const float a1 = As[(r0 + 1) * 36 + k];
            const float4 wv = *(const float4*)&Ws[k * 64 + c0];
            acc[0][0] += a0 * wv.x; acc[0][1] += a0 * wv.y;
            acc[0][2] += a0 * wv.z; acc[0][3] += a0 * wv.w;
            acc[1][0] += a1 * wv.x; acc[1][1] += a1 * wv.y;
            acc[1][2] += a1 * wv.z; acc[1][3] += a1 * wv.w;
        }
    }

    float bvv[4];
    #pragma unroll
    for (int j = 0; j < 4; j++) bvv[j] = ldm(bv_, oB + col0 + c0 + j, isbf);
    #pragma unroll
    for (int i = 0; i < 2; i++) {
        const int gr = row0 + r0 + i;
        if (gr >= M) continue;
        float4 v;
        v.x = acc[i][0] + bvv[0]; v.y = acc[i][1] + bvv[1];
        v.z = acc[i][2] + bvv[2]; v.w = acc[i][3] + bvv[3];
        *(float4*)(out + (size_t)gr * N + col0 + c0) = v;
        if (!wr) {
            const int col = col0 + c0;
            const int hh = col >> 8, cc = col & 255;
            const int gg = (gr >= NNODES) ? 1 : 0;
            const int ss = gr - gg * NNODES;
            float* tb = xlT + ((size_t)(gg * NH + hh) * CH + cc) * SPAD + ss;
            tb[0] = v.x; tb[SPAD] = v.y; tb[2 * SPAD] = v.z; tb[3 * SPAD] = v.w;
        }
    }
}

// ---------------------------------------------------------------- B: attention + LN + MLP + residual
// grid 170 = 2 graphs x 85; block owns 2 target nodes end-to-end.
__global__ __launch_bounds__(256) void k_attn_mlp(
    const float* __restrict__ xl, const float* __restrict__ xlT,
    const float* __restrict__ xr,
    const void* __restrict__ x_res, int israw,
    const void* __restrict__ att, const void* __restrict__ bias,
    const void* __restrict__ lng, const void* __restrict__ lnb,
    const void* __restrict__ W1, const void* __restrict__ b1,
    const void* __restrict__ W2, const void* __restrict__ b2,
    float* __restrict__ x_next,
    size_t oA, size_t oC, size_t oW1, size_t oB1, size_t oW2)
{
    __shared__ float s_att[NH * CH];      // 1024
    __shared__ float s_xr[2 * NH * CH];   // 2048; reused as s_part[(h*2+i)*256+c]
    __shared__ float s_alpha[8 * SPAD];   // 1408 (rows h*2+i)
    __shared__ float s_hl[2 * CH];        // 512
    __shared__ float s_m1[2 * 2 * CH];    // 1024
    const int tid = threadIdx.x, lane = tid & 63, wv = tid >> 6;
    const int isbf = sniff_bf(lng);
    const int r_bf = israw ? isbf : 0;
    const int g  = blockIdx.x / 85;
    const int d0 = (blockIdx.x % 85) * 2;

    // ---- phase 0: stage att + 2 xr rows
    for (int idx = tid; idx < NH * CH; idx += 256)
        s_att[idx] = ldm(att, oA + idx, isbf);
    {
        const int i   = tid >> 7;            // row 0/1
        const int off = (tid & 127) * 8;     // 8 floats each
        const int d   = d0 + i;
        if (d < NNODES) {
            const float* src = xr + (size_t)(g * NNODES + d) * (NH * CH) + off;
            *(float4*)&s_xr[i * 1024 + off]     = *(const float4*)(src);
            *(float4*)&s_xr[i * 1024 + off + 4] = *(const float4*)(src + 4);
        } else {
            #pragma unroll
            for (int j = 0; j < 8; j++) s_xr[i * 1024 + off + j] = 0.f;
        }
    }
    __syncthreads();

    // ---- phase 1: logits. wave = head, lanes sweep sources (3 chunks)
    {
        const int h = wv;
        const float* xpb  = xlT + ((size_t)(g * NH + h) * CH) * SPAD;
        const float* attb = s_att + h * CH;
        const float* xr0  = s_xr + h * CH;
        const float* xr1  = s_xr + 1024 + h * CH;
        for (int s3 = 0; s3 < 3; s3++) {
            const int s = lane + s3 * 64;
            if (s >= NNODES) break;
            float l0 = 0.f, l1 = 0.f;
            const float* xp = xpb + s;
            #pragma unroll 4
            for (int c = 0; c < CH; c++) {
                const float v = xp[(size_t)c * SPAD];
                const float a = attb[c];
                l0 += a * lrelu(v + xr0[c]);
                l1 += a * lrelu(v + xr1[c]);
            }
            s_alpha[(h * 2 + 0) * SPAD + s] = l0;
            s_alpha[(h * 2 + 1) * SPAD + s] = l1;
        }
    }
    __syncthreads();

    // ---- phase 2: per-row softmax (wave wv handles rows wv*2, wv*2+1)
    #pragma unroll
    for (int p = 0; p < 2; p++) {
        const int d = d0 + p;
        float* row = s_alpha + (wv * 2 + p) * SPAD;
        const int s0 = lane, s1 = lane + 64, s2 = lane + 128;
        const float l0 = (s0 < NNODES && s0 != d) ? row[s0] : -1e30f;
        const float l1 = (s1 < NNODES && s1 != d) ? row[s1] : -1e30f;
        const float l2 = (s2 < NNODES && s2 != d) ? row[s2] : -1e30f;
        float mx = fmaxf(l0, fmaxf(l1, l2));
        mx = fmaxf(mx, __shfl_xor(mx, 32)); mx = fmaxf(mx, __shfl_xor(mx, 16));
        mx = fmaxf(mx, __shfl_xor(mx, 8));  mx = fmaxf(mx, __shfl_xor(mx, 4));
        mx = fmaxf(mx, __shfl_xor(mx, 2));  mx = fmaxf(mx, __shfl_xor(mx, 1));
        const float e0 = expf(l0 - mx), e1 = expf(l1 - mx), e2 = expf(l2 - mx);
        float z = e0 + e1 + e2;
        z += __shfl_xor(z, 32); z += __shfl_xor(z, 16); z += __shfl_xor(z, 8);
        z += __shfl_xor(z, 4);  z += __shfl_xor(z, 2);  z += __shfl_xor(z, 1);
        const float sc = 0.25f / (z + 1e-16f);    // head-mean folded in
        if (d < NNODES) {
            if (s0 < NNODES) row[s0] = e0 * sc;
            if (s1 < NNODES) row[s1] = e1 * sc;
            if (s2 < NNODES) row[s2] = e2 * sc;
        }
    }
    // no sync needed: phase 3 reads only this wave's own alpha rows

    // ---- phase 3: aggregate. wave = head; lanes = channel quads
    {
        const int c4 = lane * 4;
        const float* xb  = xl + (size_t)(g * NNODES) * (NH * CH) + wv * CH + c4;
        const float* ar0 = s_alpha + (wv * 2 + 0) * SPAD;
        const float* ar1 = s_alpha + (wv * 2 + 1) * SPAD;
        float4 A0 = {0,0,0,0}, A1 = {0,0,0,0};
        for (int s = 0; s < NNODES; s++) {
            const float a0 = ar0[s], a1 = ar1[s];
            const float4 xv = *(const float4*)(xb + (size_t)s * (NH * CH));
            A0.x += a0 * xv.x; A0.y += a0 * xv.y; A0.z += a0 * xv.z; A0.w += a0 * xv.w;
            A1.x += a1 * xv.x; A1.y += a1 * xv.y; A1.z += a1 * xv.z; A1.w += a1 * xv.w;
        }
        __syncthreads();   // s_xr (logits use) is dead; safe to overwrite as s_part
        *(float4*)&s_xr[(wv * 2 + 0) * CH + c4] = A0;
        *(float4*)&s_xr[(wv * 2 + 1) * CH + c4] = A1;
    }
    __syncthreads();

    // ---- phase 4: head-sum + bias + LayerNorm (waves 0,1 = targets 0,1)
    if (wv < 2) {
        const int i = wv, c4 = lane * 4;
        float vch[4];
        float s1 = 0.f, s2 = 0.f;
        #pragma unroll
        for (int j = 0; j < 4; j++) {
            const float v = s_xr[(0 * 2 + i) * CH + c4 + j]
                          + s_xr[(1 * 2 + i) * CH + c4 + j]
                          + s_xr[(2 * 2 + i) * CH + c4 + j]
                          + s_xr[(3 * 2 + i) * CH + c4 + j]
                          + ldm(bias, oC + c4 + j, isbf);
            vch[j] = v; s1 += v; s2 += v * v;
        }
        s1 += __shfl_xor(s1, 32); s2 += __shfl_xor(s2, 32);
        s1 += __shfl_xor(s1, 16); s2 += __shfl_xor(s2, 16);
        s1 += __shfl_xor(s1, 8);  s2 += __shfl_xor(s2, 8);
        s1 += __shfl_xor(s1, 4);  s2 += __shfl_xor(s2, 4);
        s1 += __shfl_xor(s1, 2);  s2 += __shfl_xor(s2, 2);
        s1 += __shfl_xor(s1, 1);  s2 += __shfl_xor(s2, 1);
        const float mu  = s1 * (1.f / CH);
        const float var = s2 * (1.f / CH) - mu * mu;
        const float rs  = rsqrtf(var + LN_EPS);
        #pragma unroll
        for (int j = 0; j < 4; j++)
            s_hl[i * CH + c4 + j] = (vch[j] - mu) * rs * ldm(lng, oC + c4 + j, isbf)
                                  + ldm(lnb, oC + c4 + j, isbf);
    }
    __syncthreads();

    // ---- phase 5: m1 = relu(h @ W1 + b1), thread = output pair j2
    {
        const int j2 = tid * 2;
        #pragma unroll
        for (int i = 0; i < 2; i++) {
            float a0 = 0.f, a1 = 0.f;
            const float* hb = s_hl + i * CH;
            #pragma unroll 4
            for (int c = 0; c < CH; c++) {
                const float hc = hb[c];
                const float2 w = ld2(W1, oW1 + (size_t)c * (2 * CH) + j2, isbf);
                a0 += hc * w.x; a1 += hc * w.y;
            }
            const float2 bb = ld2(b1, oB1 + j2, isbf);
            s_m1[i * (2 * CH) + j2 + 0] = fmaxf(a0 + bb.x, 0.f);
            s_m1[i * (2 * CH) + j2 + 1] = fmaxf(a1 + bb.y, 0.f);
        }
    }
    __syncthreads();

    // ---- phase 6: x_next = x_res + m1 @ W2 + b2. thread = (i, channel pair)
    {
        const int i  = tid >> 7;
        const int c2 = (tid & 127) * 2;
        const int d  = d0 + i;
        float a0 = 0.f, a1 = 0.f;
        const float* mb = s_m1 + i * (2 * CH);
        #pragma unroll 4
        for (int k = 0; k < 2 * CH; k++) {
            const float m = mb[k];
            const float2 w = ld2(W2, oW2 + (size_t)k * CH + c2, isbf);
            a0 += m * w.x; a1 += m * w.y;
        }
        if (d < NNODES) {
            const float2 bb = ld2(b2, oC + c2, isbf);
            const size_t ro = (size_t)(g * NNODES + d) * CH + c2;
            const float r0v = ldm(x_res, ro, r_bf);
            const float r1v = ldm(x_res, ro + 1, r_bf);
            x_next[ro]     = a0 + bb.x + r0v;
            x_next[ro + 1] = a1 + bb.y + r1v;
        }
    }
}

// ---------------------------------------------------------------- pool
__global__ __launch_bounds__(256) void k_pool(const float* __restrict__ x,
                                              void* __restrict__ out,
                                              const void* __restrict__ lng) {
    const int isbf = sniff_bf(lng);
    const int g = blockIdx.x, c = threadIdx.x;
    float s = 0.f;
    const float* p = x + (size_t)g * NNODES * CH + c;
    for (int n = 0; n < NNODES; n++) s += p[(size_t)n * CH];
    const float v = s * (1.f / NNODES);
    if (isbf) ((bf16*)out)[g * CH + c] = __float2bfloat16(v);
    else      ((float*)out)[g * CH + c] = v;
}

// ---------------------------------------------------------------- launch
extern "C" void kernel_launch(void* const* d_in, const int* in_sizes, int n_in,
                              void* d_out, int out_size, void* d_ws, size_t ws_size,
                              hipStream_t stream)
{
    const void* x_in = d_in[0];
    const void* Wl   = d_in[1];
    const void* bl   = d_in[2];
    const void* Wr   = d_in[3];
    const void* br   = d_in[4];
    const void* att  = d_in[5];
    const void* bias = d_in[6];
    const void* lng  = d_in[7];
    const void* lnb  = d_in[8];
    const void* W1   = d_in[9];
    const void* b1   = d_in[10];
    const void* W2   = d_in[11];
    const void* b2   = d_in[12];

    float* ws  = (float*)d_ws;
    float* xl  = ws;                                  // 338*1024
    float* xr  = xl + (size_t)NNTOT * NH * CH;        // 338*1024
    float* xlT = xr + (size_t)NNTOT * NH * CH;        // 2*4*256*176
    float* xa  = xlT + (size_t)2 * NH * CH * SPAD;    // 338*256
    float* xb  = xa + (size_t)NNTOT * CH;             // 338*256

    const size_t sW  = (size_t)CH * NH * CH;
    const size_t sB  = NH * CH;
    const size_t sA  = NH * CH;
    const size_t sC  = CH;
    const size_t sW1 = (size_t)CH * 2 * CH;
    const size_t sB1 = 2 * CH;
    const size_t sW2 = (size_t)2 * CH * CH;

    const void* x_l[3] = { x_in, xa, xb };
    float*      x_o[3] = { xa, xb, xa };

    for (int l = 0; l < NL; l++) {
        const int israw = (l == 0);
        k_gemm_lr<<<dim3(11, 16, 2), 256, 0, stream>>>(
            x_l[l], israw, Wl, bl, Wr, br,
            (size_t)l * sW, (size_t)l * sB, xl, xr, xlT, lng);
        k_attn_mlp<<<dim3(170), 256, 0, stream>>>(
            xl, xlT, xr, x_l[l], israw,
            att, bias, lng, lnb, W1, b1, W2, b2, x_o[l],
            (size_t)l * sA, (size_t)l * sC,
            (size_t)l * sW1, (size_t)l * sB1, (size_t)l * sW2);
    }

    k_pool<<<dim3(2), 256, 0, stream>>>(xa, d_out, lng);
}

// Round 7
// 319.855 us; speedup vs baseline: 4.3459x; 1.9937x over previous
//
#include <hip/hip_runtime.h>
#include <hip/hip_bf16.h>

typedef __hip_bfloat16 bf16;

#define NNODES 169
#define NNTOT  338
#define CH     256
#define NH     4
#define NL     3
#define SPAD   176
#define LN_EPS 1e-5f

__device__ __forceinline__ float b2f(bf16 v) { return __bfloat162float(v); }
__device__ __forceinline__ float lrelu(float v) { return fmaxf(v, 0.2f * v); }
__device__ __forceinline__ float ldm(const void* p, size_t i, int isbf) {
    return isbf ? b2f(((const bf16*)p)[i]) : ((const float*)p)[i];
}
__device__ __forceinline__ int sniff_bf(const void* lng) {
    return ((((const unsigned*)lng)[0] & 0xFFFFu) == 0x3F80u) ? 1 : 0;
}

// ---------------------------------------------------------------- A: xl/xr GEMM
// xl = x@Wl+bl (+ transposed scatter xlT), xr = x@Wr+br. Tile 32x64, BK=32.
// grid (11,16,2); z picks Wl/Wr.
__global__ __launch_bounds__(256) void k_gemm_lr(
    const void* __restrict__ Av, int israw,
    const void* __restrict__ Wl, const void* __restrict__ bl,
    const void* __restrict__ Wr, const void* __restrict__ br,
    size_t oW, size_t oB,
    float* __restrict__ xl, float* __restrict__ xr, float* __restrict__ xlT,
    const void* __restrict__ lng)
{
    __shared__ float As[32 * 36];
    __shared__ float Ws[32 * 64];
    const int isbf  = sniff_bf(lng);
    const int a_bf  = israw ? isbf : 0;
    const int wr    = (blockIdx.z != 0);
    const void* Wv  = wr ? Wr : Wl;
    const void* bv_ = wr ? br : bl;
    float* out      = wr ? xr : xl;

    const int tid  = threadIdx.x;
    const int row0 = blockIdx.x * 32, col0 = blockIdx.y * 64;
    const int c0 = (tid & 15) * 4;
    const int r0 = (tid >> 4) * 2;
    const int ar = tid >> 3;
    const int ak = (tid & 7) * 4;
    const int wk = tid >> 3;
    const int wn = (tid & 7) * 8;
    const int K = CH, N = NH * CH, M = NNTOT;

    float acc[2][4] = {{0.f,0.f,0.f,0.f},{0.f,0.f,0.f,0.f}};

    for (int k0 = 0; k0 < K; k0 += 32) {
        float4 av = make_float4(0.f, 0.f, 0.f, 0.f);
        const int gr = row0 + ar;
        if (gr < M) {
            const size_t ai = (size_t)gr * K + k0 + ak;
            if (israw) {
                av.x = ldm(Av, ai + 0, a_bf); av.y = ldm(Av, ai + 1, a_bf);
                av.z = ldm(Av, ai + 2, a_bf); av.w = ldm(Av, ai + 3, a_bf);
            } else {
                av = *(const float4*)((const float*)Av + ai);
            }
        }
        float wv8[8];
        const size_t widx = oW + (size_t)(k0 + wk) * N + col0 + wn;
        if (isbf) {
            const int4 wi = *(const int4*)((const bf16*)Wv + widx);
            union { unsigned u; float f; } t;
            t.u = ((unsigned)wi.x) << 16;         wv8[0] = t.f;
            t.u = ((unsigned)wi.x) & 0xFFFF0000u; wv8[1] = t.f;
            t.u = ((unsigned)wi.y) << 16;         wv8[2] = t.f;
            t.u = ((unsigned)wi.y) & 0xFFFF0000u; wv8[3] = t.f;
            t.u = ((unsigned)wi.z) << 16;         wv8[4] = t.f;
            t.u = ((unsigned)wi.z) & 0xFFFF0000u; wv8[5] = t.f;
            t.u = ((unsigned)wi.w) << 16;         wv8[6] = t.f;
            t.u = ((unsigned)wi.w) & 0xFFFF0000u; wv8[7] = t.f;
        } else {
            const float* Wf = (const float*)Wv;
            const float4 w0 = *(const float4*)(Wf + widx);
            const float4 w1 = *(const float4*)(Wf + widx + 4);
            wv8[0] = w0.x; wv8[1] = w0.y; wv8[2] = w0.z; wv8[3] = w0.w;
            wv8[4] = w1.x; wv8[5] = w1.y; wv8[6] = w1.z; wv8[7] = w1.w;
        }
        __syncthreads();
        As[ar * 36 + ak + 0] = av.x; As[ar * 36 + ak + 1] = av.y;
        As[ar * 36 + ak + 2] = av.z; As[ar * 36 + ak + 3] = av.w;
        #pragma unroll
        for (int j = 0; j < 8; j++) Ws[wk * 64 + wn + j] = wv8[j];
        __syncthreads();
        #pragma unroll
        for (int k = 0; k < 32; k++) {
            const float a0 = As[r0 * 36 + k];
            const float a1 = As[(r0 + 1) * 36 + k];
            const float4 wv = *(const float4*)&Ws[k * 64 + c0];
            acc[0][0] += a0 * wv.x; acc[0][1] += a0 * wv.y;
            acc[0][2] += a0 * wv.z; acc[0][3] += a0 * wv.w;
            acc[1][0] += a1 * wv.x; acc[1][1] += a1 * wv.y;
            acc[1][2] += a1 * wv.z; acc[1][3] += a1 * wv.w;
        }
    }

    float bvv[4];
    #pragma unroll
    for (int j = 0; j < 4; j++) bvv[j] = ldm(bv_, oB + col0 + c0 + j, isbf);
    #pragma unroll
    for (int i = 0; i < 2; i++) {
        const int gr = row0 + r0 + i;
        if (gr >= M) continue;
        float4 v;
        v.x = acc[i][0] + bvv[0]; v.y = acc[i][1] + bvv[1];
        v.z = acc[i][2] + bvv[2]; v.w = acc[i][3] + bvv[3];
        *(float4*)(out + (size_t)gr * N + col0 + c0) = v;
        if (!wr) {
            const int col = col0 + c0;
            const int hh = col >> 8, cc = col & 255;
            const int gg = (gr >= NNODES) ? 1 : 0;
            const int ss = gr - gg * NNODES;
            float* tb = xlT + ((size_t)(gg * NH + hh) * CH + cc) * SPAD + ss;
            tb[0] = v.x; tb[SPAD] = v.y; tb[2 * SPAD] = v.z; tb[3 * SPAD] = v.w;
        }
    }
}

// ---------------------------------------------------------------- B: logits + softmax
// grid (85, NH, 2): block owns 2 targets for one (g,h). xlT staged to LDS in
// 32ch x 176src chunks (contiguous float4 copies); channel loop all-LDS.
// Writes alphaR[(g*4+h)*169 + d][s] rows (coalesced), head-mean 0.25/z folded.
__global__ __launch_bounds__(192) void k_logits_sm(
    const float* __restrict__ xlT, const float* __restrict__ xr,
    const void* __restrict__ att, size_t oA,
    float* __restrict__ alphaR, const void* __restrict__ lng)
{
    __shared__ float s_att[CH];
    __shared__ float s_xr[2 * CH];
    __shared__ float s_tile[32 * SPAD];
    __shared__ float s_log[2 * SPAD];
    const int isbf = sniff_bf(lng);
    const int g = blockIdx.z, h = blockIdx.y, d0 = blockIdx.x * 2;
    const int tid = threadIdx.x, lane = tid & 63, wv = tid >> 6;

    for (int idx = tid; idx < CH; idx += 192)
        s_att[idx] = ldm(att, oA + h * CH + idx, isbf);
    for (int idx = tid; idx < 2 * CH; idx += 192) {
        const int i = idx >> 8, c = idx & 255, d = d0 + i;
        s_xr[idx] = (d < NNODES)
            ? xr[(size_t)(g * NNODES + d) * (NH * CH) + h * CH + c] : 0.f;
    }

    float l0 = 0.f, l1 = 0.f;
    const int s = tid;
    const float4* src = (const float4*)(xlT + ((size_t)(g * NH + h) * CH) * SPAD);
    for (int ch = 0; ch < 8; ch++) {
        __syncthreads();
        #pragma unroll 2
        for (int i = tid; i < 32 * SPAD / 4; i += 192)
            ((float4*)s_tile)[i] = src[ch * (32 * SPAD / 4) + i];
        __syncthreads();
        if (s < NNODES) {
            const int cb = ch * 32;
            #pragma unroll
            for (int c = 0; c < 32; c++) {
                const float v = s_tile[c * SPAD + s];
                const float a = s_att[cb + c];
                l0 += a * lrelu(v + s_xr[cb + c]);
                l1 += a * lrelu(v + s_xr[CH + cb + c]);
            }
        }
    }
    if (s < NNODES) { s_log[s] = l0; s_log[SPAD + s] = l1; }
    __syncthreads();

    if (wv < 2) {
        const int d = d0 + wv;
        const float* row = s_log + wv * SPAD;
        const int s0 = lane, s1 = lane + 64, s2 = lane + 128;
        const float v0 = (s0 < NNODES && s0 != d) ? row[s0] : -1e30f;
        const float v1 = (s1 < NNODES && s1 != d) ? row[s1] : -1e30f;
        const float v2 = (s2 < NNODES && s2 != d) ? row[s2] : -1e30f;
        float mx = fmaxf(v0, fmaxf(v1, v2));
        mx = fmaxf(mx, __shfl_xor(mx, 32)); mx = fmaxf(mx, __shfl_xor(mx, 16));
        mx = fmaxf(mx, __shfl_xor(mx, 8));  mx = fmaxf(mx, __shfl_xor(mx, 4));
        mx = fmaxf(mx, __shfl_xor(mx, 2));  mx = fmaxf(mx, __shfl_xor(mx, 1));
        const float e0 = expf(v0 - mx), e1 = expf(v1 - mx), e2 = expf(v2 - mx);
        float z = e0 + e1 + e2;
        z += __shfl_xor(z, 32); z += __shfl_xor(z, 16); z += __shfl_xor(z, 8);
        z += __shfl_xor(z, 4);  z += __shfl_xor(z, 2);  z += __shfl_xor(z, 1);
        const float sc = 0.25f / (z + 1e-16f);
        if (d < NNODES) {
            float* arow = alphaR + ((size_t)(g * NH + h) * NNODES + d) * SPAD;
            if (s0 < NNODES) arow[s0] = e0 * sc;
            if (s1 < NNODES) arow[s1] = e1 * sc;
            if (s2 < NNODES) arow[s2] = e2 * sc;
        }
    }
}

// ---------------------------------------------------------------- C: aggregate as GEMM
// part[h][g*169+d][c] = sum_s alpha[d,s] * xl[s, h*256+c], per (g,h).
// grid (6 d-tiles of 32, 4 c-tiles of 64, 8 gh). K = sources, BK=32.
__global__ __launch_bounds__(256) void k_agg(
    const float* __restrict__ alphaR, const float* __restrict__ xl,
    float* __restrict__ part)
{
    __shared__ float s_a[32 * 33];
    __shared__ float s_x[32 * 64];
    const int gh = blockIdx.z, g = gh >> 2, h = gh & 3;
    const int d0 = blockIdx.x * 32, c0 = blockIdx.y * 64;
    const int tid = threadIdx.x;
    const int dr = (tid >> 4) * 2, cq = (tid & 15) * 4;
    const int sr = tid >> 3, sc4 = (tid & 7) * 4;
    const int xc8 = (tid & 7) * 8;

    float acc[2][4] = {{0.f,0.f,0.f,0.f},{0.f,0.f,0.f,0.f}};

    for (int s0 = 0; s0 < NNODES; s0 += 32) {
        __syncthreads();
        {   // alpha tile [32d][32s], zero-padded
            const int d = d0 + sr;
            const float* ap = alphaR + ((size_t)gh * NNODES + d) * SPAD + s0 + sc4;
            const int ok = (d < NNODES);
            s_a[sr * 33 + sc4 + 0] = (ok && s0 + sc4 + 0 < NNODES) ? ap[0] : 0.f;
            s_a[sr * 33 + sc4 + 1] = (ok && s0 + sc4 + 1 < NNODES) ? ap[1] : 0.f;
            s_a[sr * 33 + sc4 + 2] = (ok && s0 + sc4 + 2 < NNODES) ? ap[2] : 0.f;
            s_a[sr * 33 + sc4 + 3] = (ok && s0 + sc4 + 3 < NNODES) ? ap[3] : 0.f;
        }
        {   // x tile [32s][64c]
            const int sg = s0 + sr;
            if (sg < NNODES) {
                const float* xp = xl + (size_t)(g * NNODES + sg) * (NH * CH) + h * CH + c0 + xc8;
                *(float4*)&s_x[sr * 64 + xc8]     = *(const float4*)(xp);
                *(float4*)&s_x[sr * 64 + xc8 + 4] = *(const float4*)(xp + 4);
            } else {
                #pragma unroll
                for (int j = 0; j < 8; j++) s_x[sr * 64 + xc8 + j] = 0.f;
            }
        }
        __syncthreads();
        #pragma unroll
        for (int k = 0; k < 32; k++) {
            const float a0 = s_a[(dr + 0) * 33 + k];
            const float a1 = s_a[(dr + 1) * 33 + k];
            const float4 xv = *(const float4*)&s_x[k * 64 + cq];
            acc[0][0] += a0 * xv.x; acc[0][1] += a0 * xv.y;
            acc[0][2] += a0 * xv.z; acc[0][3] += a0 * xv.w;
            acc[1][0] += a1 * xv.x; acc[1][1] += a1 * xv.y;
            acc[1][2] += a1 * xv.z; acc[1][3] += a1 * xv.w;
        }
    }
    #pragma unroll
    for (int i = 0; i < 2; i++) {
        const int d = d0 + dr + i;
        if (d >= NNODES) continue;
        float4 v;
        v.x = acc[i][0]; v.y = acc[i][1]; v.z = acc[i][2]; v.w = acc[i][3];
        *(float4*)(part + ((size_t)h * NNTOT + g * NNODES + d) * CH + c0 + cq) = v;
    }
}

// ---------------------------------------------------------------- D: head-sum + LN
__global__ __launch_bounds__(256) void k_ln(
    const float* __restrict__ part,
    const void* __restrict__ bias, size_t oB,
    const void* __restrict__ ln_g, size_t oG,
    const void* __restrict__ ln_b, size_t oBt,
    float* __restrict__ h_out, const void* __restrict__ lng)
{
    __shared__ float s_red[8];
    const int isbf = sniff_bf(lng);
    const int node = blockIdx.x, c = threadIdx.x;
    const int lane = c & 63, wv = c >> 6;

    float vch = part[((size_t)0 * NNTOT + node) * CH + c]
              + part[((size_t)1 * NNTOT + node) * CH + c]
              + part[((size_t)2 * NNTOT + node) * CH + c]
              + part[((size_t)3 * NNTOT + node) * CH + c]
              + ldm(bias, oB + c, isbf);

    float s1 = vch, s2 = vch * vch;
    s1 += __shfl_xor(s1, 32); s2 += __shfl_xor(s2, 32);
    s1 += __shfl_xor(s1, 16); s2 += __shfl_xor(s2, 16);
    s1 += __shfl_xor(s1, 8);  s2 += __shfl_xor(s2, 8);
    s1 += __shfl_xor(s1, 4);  s2 += __shfl_xor(s2, 4);
    s1 += __shfl_xor(s1, 2);  s2 += __shfl_xor(s2, 2);
    s1 += __shfl_xor(s1, 1);  s2 += __shfl_xor(s2, 1);
    if (lane == 0) { s_red[wv] = s1; s_red[4 + wv] = s2; }
    __syncthreads();
    const float S1 = s_red[0] + s_red[1] + s_red[2] + s_red[3];
    const float S2 = s_red[4] + s_red[5] + s_red[6] + s_red[7];
    const float mu  = S1 * (1.f / CH);
    const float var = S2 * (1.f / CH) - mu * mu;
    const float o = (vch - mu) * rsqrtf(var + LN_EPS) * ldm(ln_g, oG + c, isbf)
                  + ldm(ln_b, oBt + c, isbf);
    h_out[(size_t)node * CH + c] = o;
}

// ---------------------------------------------------------------- E: MLP1 (relu)
// m1 = relu(h_ln @ W1 + b1). Tile 32x32, grid (11,16), K=256.
__global__ __launch_bounds__(256) void k_mlp1(
    const float* __restrict__ A, const void* __restrict__ W, size_t oW,
    const void* __restrict__ b, size_t oB,
    float* __restrict__ out, const void* __restrict__ lng)
{
    __shared__ float As[32 * 36];
    __shared__ float Ws[32 * 32];
    const int isbf = sniff_bf(lng);
    const int tid = threadIdx.x;
    const int row0 = blockIdx.x * 32, col0 = blockIdx.y * 32;
    const int row = tid >> 3, c4 = (tid & 7) * 4;
    const int K = CH, N = 2 * CH, M = NNTOT;

    float acc[4] = {0.f, 0.f, 0.f, 0.f};

    for (int k0 = 0; k0 < K; k0 += 32) {
        float4 av = make_float4(0.f, 0.f, 0.f, 0.f);
        const int gr = row0 + row;
        if (gr < M) av = *(const float4*)(A + (size_t)gr * K + k0 + c4);
        float wv4[4];
        const size_t widx = oW + (size_t)(k0 + row) * N + col0 + c4;
        if (isbf) {
            const int2 wi = *(const int2*)((const bf16*)W + widx);
            union { unsigned u; float f; } t;
            t.u = ((unsigned)wi.x) << 16;         wv4[0] = t.f;
            t.u = ((unsigned)wi.x) & 0xFFFF0000u; wv4[1] = t.f;
            t.u = ((unsigned)wi.y) << 16;         wv4[2] = t.f;
            t.u = ((unsigned)wi.y) & 0xFFFF0000u; wv4[3] = t.f;
        } else {
            const float4 w0 = *(const float4*)((const float*)W + widx);
            wv4[0] = w0.x; wv4[1] = w0.y; wv4[2] = w0.z; wv4[3] = w0.w;
        }
        __syncthreads();
        As[row * 36 + c4 + 0] = av.x; As[row * 36 + c4 + 1] = av.y;
        As[row * 36 + c4 + 2] = av.z; As[row * 36 + c4 + 3] = av.w;
        #pragma unroll
        for (int j = 0; j < 4; j++) Ws[row * 32 + c4 + j] = wv4[j];
        __syncthreads();
        #pragma unroll
        for (int k = 0; k < 32; k++) {
            const float a = As[row * 36 + k];
            const float4 wv = *(const float4*)&Ws[k * 32 + c4];
            acc[0] += a * wv.x; acc[1] += a * wv.y;
            acc[2] += a * wv.z; acc[3] += a * wv.w;
        }
    }
    const int gr = row0 + row;
    if (gr < M) {
        float4 v;
        v.x = fmaxf(acc[0] + ldm(b, oB + col0 + c4 + 0, isbf), 0.f);
        v.y = fmaxf(acc[1] + ldm(b, oB + col0 + c4 + 1, isbf), 0.f);
        v.z = fmaxf(acc[2] + ldm(b, oB + col0 + c4 + 2, isbf), 0.f);
        v.w = fmaxf(acc[3] + ldm(b, oB + col0 + c4 + 3, isbf), 0.f);
        *(float4*)(out + (size_t)gr * N + col0 + c4) = v;
    }
}

// ---------------------------------------------------------------- F: MLP2 + residual
// x_next = x_res + m1 @ W2 + b2. Tile 16x32, grid (22,8), K=512.
__global__ __launch_bounds__(256) void k_mlp2(
    const float* __restrict__ A, const void* __restrict__ W, size_t oW,
    const void* __restrict__ b, size_t oB,
    const void* __restrict__ x_res, int israw,
    float* __restrict__ out, const void* __restrict__ lng)
{
    __shared__ float As[16 * 34];
    __shared__ float Ws[32 * 32];
    const int isbf = sniff_bf(lng);
    const int r_bf = israw ? isbf : 0;
    const int tid = threadIdx.x;
    const int row0 = blockIdx.x * 16, col0 = blockIdx.y * 32;
    const int row = tid >> 4, c2 = (tid & 15) * 2;
    const int wk = tid >> 3, wc4 = (tid & 7) * 4;
    const int K = 2 * CH, N = CH, M = NNTOT;

    float acc[2] = {0.f, 0.f};

    for (int k0 = 0; k0 < K; k0 += 32) {
        float2 av = make_float2(0.f, 0.f);
        const int gr = row0 + row;
        if (gr < M) av = *(const float2*)(A + (size_t)gr * K + k0 + c2);
        float wv4[4];
        const size_t widx = oW + (size_t)(k0 + wk) * N + col0 + wc4;
        if (isbf) {
            const int2 wi = *(const int2*)((const bf16*)W + widx);
            union { unsigned u; float f; } t;
            t.u = ((unsigned)wi.x) << 16;         wv4[0] = t.f;
            t.u = ((unsigned)wi.x) & 0xFFFF0000u; wv4[1] = t.f;
            t.u = ((unsigned)wi.y) << 16;         wv4[2] = t.f;
            t.u = ((unsigned)wi.y) & 0xFFFF0000u; wv4[3] = t.f;
        } else {
            const float4 w0 = *(const float4*)((const float*)W + widx);
            wv4[0] = w0.x; wv4[1] = w0.y; wv4[2] = w0.z; wv4[3] = w0.w;
        }
        __syncthreads();
        As[row * 34 + c2 + 0] = av.x; As[row * 34 + c2 + 1] = av.y;
        #pragma unroll
        for (int j = 0; j < 4; j++) Ws[wk * 32 + wc4 + j] = wv4[j];
        __syncthreads();
        #pragma unroll
        for (int k = 0; k < 32; k++) {
            const float a = As[row * 34 + k];
            const float2 wv = *(const float2*)&Ws[k * 32 + c2];
            acc[0] += a * wv.x; acc[1] += a * wv.y;
        }
    }
    const int gr = row0 + row;
    if (gr < M) {
        const size_t ro = (size_t)gr * N + col0 + c2;
        const float o0 = acc[0] + ldm(b, oB + col0 + c2 + 0, isbf) + ldm(x_res, ro, r_bf);
        const float o1 = acc[1] + ldm(b, oB + col0 + c2 + 1, isbf) + ldm(x_res, ro + 1, r_bf);
        out[ro]     = o0;
        out[ro + 1] = o1;
    }
}

// ---------------------------------------------------------------- pool
__global__ __launch_bounds__(256) void k_pool(const float* __restrict__ x,
                                              void* __restrict__ out,
                                              const void* __restrict__ lng) {
    const int isbf = sniff_bf(lng);
    const int g = blockIdx.x, c = threadIdx.x;
    float s = 0.f;
    const float* p = x + (size_t)g * NNODES * CH + c;
    for (int n = 0; n < NNODES; n++) s += p[(size_t)n * CH];
    const float v = s * (1.f / NNODES);
    if (isbf) ((bf16*)out)[g * CH + c] = __float2bfloat16(v);
    else      ((float*)out)[g * CH + c] = v;
}

// ---------------------------------------------------------------- launch
extern "C" void kernel_launch(void* const* d_in, const int* in_sizes, int n_in,
                              void* d_out, int out_size, void* d_ws, size_t ws_size,
                              hipStream_t stream)
{
    const void* x_in = d_in[0];
    const void* Wl   = d_in[1];
    const void* bl   = d_in[2];
    const void* Wr   = d_in[3];
    const void* br   = d_in[4];
    const void* att  = d_in[5];
    const void* bias = d_in[6];
    const void* lng  = d_in[7];
    const void* lnb  = d_in[8];
    const void* W1   = d_in[9];
    const void* b1   = d_in[10];
    const void* W2   = d_in[11];
    const void* b2   = d_in[12];

    float* ws     = (float*)d_ws;
    float* xl     = ws;                                      // 338*1024
    float* xr     = xl + (size_t)NNTOT * NH * CH;            // 338*1024
    float* xlT    = xr + (size_t)NNTOT * NH * CH;            // 2*4*256*176
    float* alphaR = xlT + (size_t)2 * NH * CH * SPAD;        // 2*4*169*176
    float* part   = alphaR + (size_t)2 * NH * NNODES * SPAD; // 4*338*256
    float* h_ln   = part + (size_t)NH * NNTOT * CH;          // 338*256
    float* m1     = h_ln + (size_t)NNTOT * CH;               // 338*512
    float* xa     = m1 + (size_t)NNTOT * 2 * CH;             // 338*256
    float* xb     = xa + (size_t)NNTOT * CH;                 // 338*256

    const size_t sW  = (size_t)CH * NH * CH;
    const size_t sB  = NH * CH;
    const size_t sA  = NH * CH;
    const size_t sC  = CH;
    const size_t sW1 = (size_t)CH * 2 * CH;
    const size_t sB1 = 2 * CH;
    const size_t sW2 = (size_t)2 * CH * CH;

    const void* x_l[3] = { x_in, xa, xb };
    float*      x_o[3] = { xa, xb, xa };

    for (int l = 0; l < NL; l++) {
        const int israw = (l == 0);
        k_gemm_lr<<<dim3(11, 16, 2), 256, 0, stream>>>(
            x_l[l], israw, Wl, bl, Wr, br,
            (size_t)l * sW, (size_t)l * sB, xl, xr, xlT, lng);
        k_logits_sm<<<dim3(85, NH, 2), 192, 0, stream>>>(
            xlT, xr, att, (size_t)l * sA, alphaR, lng);
        k_agg<<<dim3(6, 4, 8), 256, 0, stream>>>(alphaR, xl, part);
        k_ln<<<dim3(NNTOT), 256, 0, stream>>>(
            part, bias, (size_t)l * sC, lng, (size_t)l * sC, lnb, (size_t)l * sC,
            h_ln, lng);
        k_mlp1<<<dim3(11, 16), 256, 0, stream>>>(
            h_ln, W1, (size_t)l * sW1, b1, (size_t)l * sB1, m1, lng);
        k_mlp2<<<dim3(22, 8), 256, 0, stream>>>(
            m1, W2, (size_t)l * sW2, b2, (size_t)l * sC,
            x_l[l], israw, x_o[l], lng);
    }

    k_pool<<<dim3(2), 256, 0, stream>>>(xa, d_out, lng);
}